// Round 1
// baseline (691.336 us; speedup 1.0000x reference)
//
#include <hip/hip_runtime.h>
#include <stdint.h>

#define GSZ 60
#define KNB 13
#define NPT 512

typedef __attribute__((ext_vector_type(4))) float f32x4;
typedef __attribute__((ext_vector_type(8))) short s16x8;

__device__ __forceinline__ ushort f2bf(float f) {
  union { float f; unsigned u; } v; v.f = f;
  unsigned r = v.u + 0x7fffu + ((v.u >> 16) & 1u);
  return (ushort)(r >> 16);
}
__device__ __forceinline__ float bf2f(ushort h) {
  union { unsigned u; float f; } v; v.u = ((unsigned)h) << 16;
  return v.f;
}

// feats [N][32][G] fp32 -> X0 [G][N][32] bf16
__global__ __launch_bounds__(256) void prep_feats_k(const float* __restrict__ feats,
                                                    ushort* __restrict__ X0) {
  int idx = blockIdx.x * 256 + threadIdx.x;
  if (idx >= GSZ * NPT * 32) return;
  int c = idx & 31;
  int t = idx >> 5;
  int n = t % NPT;
  int g = t / NPT;
  X0[idx] = f2bf(feats[(n * 32 + c) * GSZ + g]);
}

// W [O][C][K] fp32 -> Wl [K][Opad][C] bf16 (zero-padded rows o>=O)
__global__ __launch_bounds__(256) void prep_w_k(const float* __restrict__ W,
                                                ushort* __restrict__ Wl,
                                                int O, int Opad, int C) {
  int idx = blockIdx.x * 256 + threadIdx.x;
  if (idx >= KNB * Opad * C) return;
  int c = idx % C;
  int t = idx / C;
  int o = t % Opad;
  int k = t / Opad;
  Wl[idx] = (o < O) ? f2bf(W[(o * C + c) * KNB + k]) : (ushort)0;
}

// Generic comb layer: out[g][n][o] = sum_{k,c} Xin[nei[g,k]][n][c] * W[o][c][k]
// MODE 0: Xout = bf16(acc + bias)        (optional RELU)
// MODE 1: Xout = bf16(Xout + acc + bias) (in-place residual accumulate)
// MODE 2: Eq[g][n][ocol] = acc + bias + feats[n][ocol][g]   (fp32, ocol<OREAL gets feats/bias)
template <int CIN, int OPAD, int OREAL, int MODE, bool RELU>
__global__ __launch_bounds__(256) void comb_gemm(
    const ushort* __restrict__ Xin,   // [G][N][CIN] bf16
    const ushort* __restrict__ Wl,    // [K][OPAD][CIN] bf16
    const float* __restrict__ bias,   // [OREAL]
    const int* __restrict__ nei,      // [G*K]
    ushort* __restrict__ Xout,        // modes 0/1: [G][N][OPAD] bf16
    float* __restrict__ Eq,           // mode 2: [G][N][64] fp32
    const float* __restrict__ feats)  // mode 2: [N][32][G] fp32
{
  static_assert(CIN % 32 == 0, "CIN multiple of 32");
  const int g = blockIdx.z;
  const int n0 = blockIdx.y * 64;
  const int o0 = blockIdx.x * 64;
  const int t = threadIdx.x;
  const int wave = t >> 6;
  const int lane = t & 63;
  const int lrow = lane & 15;   // row/col within fragment
  const int lkg = lane >> 4;    // k-group 0..3

  __shared__ ushort As[64][40];  // +8 pad: 80B row stride -> ~2-way LDS conflicts (free)
  __shared__ ushort Bs[64][40];

  f32x4 acc[4] = {f32x4{0.f, 0.f, 0.f, 0.f}, f32x4{0.f, 0.f, 0.f, 0.f},
                  f32x4{0.f, 0.f, 0.f, 0.f}, f32x4{0.f, 0.f, 0.f, 0.f}};

  const int srow = t >> 2;         // 0..63 staging row
  const int sseg = (t & 3) * 8;    // 16B segment

  int neis[KNB];
#pragma unroll
  for (int k = 0; k < KNB; ++k) neis[k] = nei[g * KNB + k];

  for (int k = 0; k < KNB; ++k) {
    const ushort* Xsrc = Xin + ((size_t)neis[k] * NPT + n0) * CIN;
    const ushort* Wsrc = Wl + ((size_t)k * OPAD + o0) * CIN;
#pragma unroll 1
    for (int c0 = 0; c0 < CIN; c0 += 32) {
      *(uint4*)&As[srow][sseg] = *(const uint4*)&Xsrc[srow * CIN + c0 + sseg];
      *(uint4*)&Bs[srow][sseg] = *(const uint4*)&Wsrc[srow * CIN + c0 + sseg];
      __syncthreads();
      s16x8 bfrag = *(const s16x8*)&Bs[wave * 16 + lrow][lkg * 8];
#pragma unroll
      for (int nb = 0; nb < 4; ++nb) {
        s16x8 afrag = *(const s16x8*)&As[nb * 16 + lrow][lkg * 8];
        acc[nb] = __builtin_amdgcn_mfma_f32_16x16x32_bf16(afrag, bfrag, acc[nb], 0, 0, 0);
      }
      __syncthreads();
    }
  }

  const int ocol = o0 + wave * 16 + lrow;
  float bv;
  if (MODE == 2)
    bv = (ocol < OREAL) ? bias[ocol] : 0.f;
  else
    bv = bias[ocol];

#pragma unroll
  for (int nb = 0; nb < 4; ++nb) {
#pragma unroll
    for (int r = 0; r < 4; ++r) {
      const int row = n0 + nb * 16 + lkg * 4 + r;
      float v = acc[nb][r] + bv;
      if (MODE == 0) {
        if (RELU) v = v > 0.f ? v : 0.f;
        Xout[((size_t)g * NPT + row) * OPAD + ocol] = f2bf(v);
      } else if (MODE == 1) {
        const size_t idx = ((size_t)g * NPT + row) * OPAD + ocol;
        Xout[idx] = f2bf(bf2f(Xout[idx]) + v);
      } else {
        const float add = (ocol < OREAL) ? feats[((size_t)row * 32 + ocol) * GSZ + g] : 0.f;
        Eq[((size_t)g * NPT + row) * 64 + ocol] = v + add;
      }
    }
  }
}

// Eq [G][N][64] fp32 -> out: inv [N][32] normalized, eqv [N][32][G] normalized
__global__ __launch_bounds__(256) void finalize_k(const float* __restrict__ Eq,
                                                  float* __restrict__ out) {
  const int n = blockIdx.x;
  const int t = threadIdx.x;
  const int c = t & 31;
  const int gs = t >> 5;  // 0..7

  float invp = 0.f;
  for (int g = gs; g < GSZ; g += 8) {
    float x = Eq[((size_t)g * NPT + n) * 64 + c];
    invp += x;
    float ss = x * x;
#pragma unroll
    for (int m = 16; m >= 1; m >>= 1) ss += __shfl_xor(ss, m, 64);
    float nrm = sqrtf(ss);
    nrm = nrm > 1e-4f ? nrm : 1e-4f;
    out[16384 + ((size_t)n * 32 + c) * GSZ + g] = x / nrm;
  }

  __shared__ float tmp[8][32];
  tmp[gs][c] = invp;
  __syncthreads();
  if (t < 32) {
    float s = 0.f;
#pragma unroll
    for (int i = 0; i < 8; ++i) s += tmp[i][t];
    s *= (1.f / 60.f);
    float ss = s * s;
#pragma unroll
    for (int m = 16; m >= 1; m >>= 1) ss += __shfl_xor(ss, m, 64);
    float nrm = sqrtf(ss);
    nrm = nrm > 1e-4f ? nrm : 1e-4f;
    out[(size_t)n * 32 + t] = s / nrm;
  }
}

extern "C" void kernel_launch(void* const* d_in, const int* in_sizes, int n_in,
                              void* d_out, int out_size, void* d_ws, size_t ws_size,
                              hipStream_t stream) {
  const float* feats = (const float*)d_in[0];
  const int* nei = (const int*)d_in[1];
  const float* W_in = (const float*)d_in[2];
  const float* b_in = (const float*)d_in[3];
  const float* W_r1 = (const float*)d_in[4];
  const float* b_r1 = (const float*)d_in[5];
  const float* W_r2 = (const float*)d_in[6];
  const float* b_r2 = (const float*)d_in[7];
  const float* W_out = (const float*)d_in[8];
  const float* b_out = (const float*)d_in[9];
  float* out = (float*)d_out;

  char* ws = (char*)d_ws;
  size_t off = 0;
  auto alloc = [&](size_t bytes) {
    void* p = ws + off;
    off += (bytes + 255) & ~(size_t)255;
    return p;
  };
  ushort* X0 = (ushort*)alloc((size_t)GSZ * NPT * 32 * 2);       // 1.97 MB
  ushort* H1 = (ushort*)alloc((size_t)GSZ * NPT * 256 * 2);      // 15.7 MB (h1, then h2 in-place)
  ushort* R = (ushort*)alloc((size_t)GSZ * NPT * 512 * 2);       // 31.5 MB
  float* Eq = (float*)alloc((size_t)GSZ * NPT * 64 * 4);         // 7.9 MB
  ushort* Wl_in = (ushort*)alloc((size_t)KNB * 256 * 32 * 2);
  ushort* Wl_r1 = (ushort*)alloc((size_t)KNB * 512 * 256 * 2);
  ushort* Wl_r2 = (ushort*)alloc((size_t)KNB * 256 * 512 * 2);
  ushort* Wl_out = (ushort*)alloc((size_t)KNB * 64 * 256 * 2);

  // prep (every call; deterministic)
  prep_feats_k<<<(GSZ * NPT * 32 + 255) / 256, 256, 0, stream>>>(feats, X0);
  prep_w_k<<<(KNB * 256 * 32 + 255) / 256, 256, 0, stream>>>(W_in, Wl_in, 256, 256, 32);
  prep_w_k<<<(KNB * 512 * 256 + 255) / 256, 256, 0, stream>>>(W_r1, Wl_r1, 512, 512, 256);
  prep_w_k<<<(KNB * 256 * 512 + 255) / 256, 256, 0, stream>>>(W_r2, Wl_r2, 256, 256, 512);
  prep_w_k<<<(KNB * 64 * 256 + 255) / 256, 256, 0, stream>>>(W_out, Wl_out, 32, 64, 256);

  dim3 blk(256);
  // L1: 32 -> 256, h1
  comb_gemm<32, 256, 256, 0, false><<<dim3(4, 8, GSZ), blk, 0, stream>>>(
      X0, Wl_in, b_in, nei, H1, nullptr, nullptr);
  // L2: 256 -> 512, relu -> r
  comb_gemm<256, 512, 512, 0, true><<<dim3(8, 8, GSZ), blk, 0, stream>>>(
      H1, Wl_r1, b_r1, nei, R, nullptr, nullptr);
  // L3: 512 -> 256, h2 = h1 + comb(r) (in-place into H1)
  comb_gemm<512, 256, 256, 1, false><<<dim3(4, 8, GSZ), blk, 0, stream>>>(
      R, Wl_r2, b_r2, nei, H1, nullptr, nullptr);
  // L4: 256 -> 32 (padded 64), + feats -> Eq fp32
  comb_gemm<256, 64, 32, 2, false><<<dim3(1, 8, GSZ), blk, 0, stream>>>(
      H1, Wl_out, b_out, nei, nullptr, Eq, feats);
  // epilogue: mean + both normalizations
  finalize_k<<<NPT, 256, 0, stream>>>(Eq, out);
}

// Round 2
// 355.833 us; speedup vs baseline: 1.9429x; 1.9429x over previous
//
#include <hip/hip_runtime.h>
#include <stdint.h>

#define GSZ 60
#define KNB 13
#define NPT 512

typedef __attribute__((ext_vector_type(4))) float f32x4;
typedef __attribute__((ext_vector_type(8))) short s16x8;

__device__ __forceinline__ ushort f2bf(float f) {
  union { float f; unsigned u; } v; v.f = f;
  unsigned r = v.u + 0x7fffu + ((v.u >> 16) & 1u);
  return (ushort)(r >> 16);
}
__device__ __forceinline__ float bf2f(ushort h) {
  union { unsigned u; float f; } v; v.u = ((unsigned)h) << 16;
  return v.f;
}

// async global->LDS, 16B per lane; dst must be wave-uniform (HW adds lane*16)
__device__ __forceinline__ void gload_lds16(const void* gsrc, void* ldst) {
  __builtin_amdgcn_global_load_lds(
      (const __attribute__((address_space(1))) uint32_t*)gsrc,
      (__attribute__((address_space(3))) uint32_t*)ldst, 16, 0, 0);
}

// feats [N][32][G] fp32 -> X0 [61][N][32] bf16 (panel 60 = zeros, L1 K-padding)
__global__ __launch_bounds__(256) void prep_feats_k(const float* __restrict__ feats,
                                                    ushort* __restrict__ X0) {
  int idx = blockIdx.x * 256 + threadIdx.x;
  if (idx >= 61 * NPT * 32) return;
  int c = idx & 31;
  int t = idx >> 5;
  int n = t % NPT;
  int g = t / NPT;
  X0[idx] = (g < GSZ) ? f2bf(feats[(n * 32 + c) * GSZ + g]) : (ushort)0;
}

// W [O][C][13] fp32 -> Wb [OPAD][KPAD] bf16, Wb[o][k*C+c] = W[o][c][k], zero-padded
__global__ __launch_bounds__(256) void prep_wb_k(const float* __restrict__ W,
                                                 ushort* __restrict__ Wb,
                                                 int O, int OPAD, int C, int KPAD) {
  int idx = blockIdx.x * 256 + threadIdx.x;
  if (idx >= OPAD * KPAD) return;
  int o = idx / KPAD;
  int kk = idx - o * KPAD;
  int k = kk / C;
  int c = kk - k * C;
  Wb[idx] = (o < O && k < KNB) ? f2bf(W[(o * C + c) * KNB + k]) : (ushort)0;
}

// out[g][n][o] = sum_kk Xin[nei[g, kk/CIN]][n][kk%CIN] * Wb[o][kk]
// m97-class: BM=128 x BN tile, BK=64, global_load_lds(16) staging,
// XOR-swizzled LDS (linear dest + inverse-swizzled source + swizzled read).
// MODE 0: Xout = bf16(acc+bias) (opt RELU); MODE 1: Xout += ...; MODE 2: Eq fp32 (+feats)
template <int CIN, int KTOT, int OPAD, int OREAL, int BN, int MODE, bool RELU>
__global__ __launch_bounds__(256) void comb_gemm(
    const ushort* __restrict__ Xin,   // [P][NPT][CIN] bf16 panels
    const ushort* __restrict__ Wb,    // [OPAD][KTOT] bf16
    const float* __restrict__ bias,
    const int* __restrict__ nei,      // [G*13]
    ushort* __restrict__ Xout,        // modes 0/1: [G][NPT][OPAD]
    float* __restrict__ Eq,           // mode 2: [G][NPT][64] fp32
    const float* __restrict__ feats)  // mode 2: [N][32][G] fp32
{
  constexpr int BM = 128;
  constexpr int BK = 64;
  constexpr int NCH = KTOT / BK;
  constexpr int TO = OPAD / BN;
  constexpr int TN = NPT / BM;  // 4
  constexpr int WN = BN / 2;    // per-wave n-width
  constexpr int N_REP = WN / 16;
  constexpr int M_REP = 4;  // 64/16
  constexpr int CSH = (CIN == 32) ? 5 : (CIN == 256) ? 8 : 9;
  static_assert(CIN == (1 << CSH), "CIN pow2");

  __shared__ ushort smA[BM * BK];
  __shared__ ushort smB[BN * BK];
  __shared__ int nei_sh[16];

  // XCD-chunked swizzle: consecutive idx (same g) land on the same XCD,
  // so the 13 gathered A-panels of a g stay resident in that XCD's L2.
  const int nwg = TO * TN * GSZ;
  const int cpx = nwg >> 3;
  const int bid = blockIdx.x;
  const int idx = (bid & 7) * cpx + (bid >> 3);
  const int g = idx / (TO * TN);
  const int rem = idx - g * (TO * TN);
  const int nt = rem / TO;
  const int ot = rem - nt * TO;
  const int n0 = nt * BM;
  const int o0 = ot * BN;

  const int t = threadIdx.x;
  if (t < 14) nei_sh[t] = (t < KNB) ? nei[g * KNB + t] : GSZ;  // 13 -> zero panel (L1 pad)
  __syncthreads();

  const int w = t >> 6;
  const int l = t & 63;
  const int lrow = l & 15;
  const int lkg = l >> 4;
  const int wr = w >> 1;
  const int wc = w & 1;
  const int srow_w = w * 8;   // wave-uniform row base
  const int sr = l >> 3;      // lane row 0..7 within wave
  const int slot = l & 7;     // 16B slot 0..7

  f32x4 acc[M_REP][N_REP] = {};

#pragma unroll 1
  for (int q = 0; q < NCH; ++q) {
    const int c0 = q * BK;
    // stage A [BM][BK]: linear LDS dest, source column pre-inverse-swizzled
#pragma unroll
    for (int j = 0; j < BM / 32; ++j) {
      const int r = j * 32 + srow_w + sr;
      const int kk = c0 + ((slot ^ (r & 7)) << 3);
      const int nbr = kk >> CSH;
      const int cc = kk & (CIN - 1);
      const ushort* src = Xin + (((size_t)nei_sh[nbr] * NPT + n0 + r) << CSH) + cc;
      gload_lds16(src, &smA[(j * 32 + srow_w) * BK]);
    }
    // stage B [BN][BK]
#pragma unroll
    for (int j = 0; j < BN / 32; ++j) {
      const int r = j * 32 + srow_w + sr;
      const int kk = c0 + ((slot ^ (r & 7)) << 3);
      const ushort* src = Wb + (size_t)(o0 + r) * KTOT + kk;
      gload_lds16(src, &smB[(j * 32 + srow_w) * BK]);
    }
    __syncthreads();  // compiler drains vmcnt before barrier
#pragma unroll
    for (int ks = 0; ks < 2; ++ks) {
      const int cb = ks * 4 + lkg;
      s16x8 bf[N_REP];
#pragma unroll
      for (int n = 0; n < N_REP; ++n) {
        const int r = wc * WN + n * 16 + lrow;
        bf[n] = *(const s16x8*)&smB[r * BK + ((cb ^ (r & 7)) << 3)];
      }
#pragma unroll
      for (int m = 0; m < M_REP; ++m) {
        const int r = wr * 64 + m * 16 + lrow;
        s16x8 af = *(const s16x8*)&smA[r * BK + ((cb ^ (r & 7)) << 3)];
#pragma unroll
        for (int n = 0; n < N_REP; ++n)
          acc[m][n] = __builtin_amdgcn_mfma_f32_16x16x32_bf16(af, bf[n], acc[m][n], 0, 0, 0);
      }
    }
    __syncthreads();
  }

#pragma unroll
  for (int m = 0; m < M_REP; ++m) {
#pragma unroll
    for (int n = 0; n < N_REP; ++n) {
      const int oc = o0 + wc * WN + n * 16 + lrow;
      float bv;
      if (MODE == 2)
        bv = (oc < OREAL) ? bias[oc] : 0.f;
      else
        bv = bias[oc];
#pragma unroll
      for (int r = 0; r < 4; ++r) {
        const int row = n0 + wr * 64 + m * 16 + lkg * 4 + r;
        float v = acc[m][n][r] + bv;
        if (MODE == 0) {
          if (RELU) v = v > 0.f ? v : 0.f;
          Xout[((size_t)g * NPT + row) * OPAD + oc] = f2bf(v);
        } else if (MODE == 1) {
          const size_t ix = ((size_t)g * NPT + row) * OPAD + oc;
          Xout[ix] = f2bf(bf2f(Xout[ix]) + v);
        } else {
          const float add = (oc < OREAL) ? feats[((size_t)row * 32 + oc) * GSZ + g] : 0.f;
          Eq[((size_t)g * NPT + row) * 64 + oc] = v + add;
        }
      }
    }
  }
}

// Eq [G][N][64] fp32 -> out: inv [N][32] normalized, eqv [N][32][G] normalized
__global__ __launch_bounds__(256) void finalize_k(const float* __restrict__ Eq,
                                                  float* __restrict__ out) {
  const int n = blockIdx.x;
  const int t = threadIdx.x;
  const int c = t & 31;
  const int gs = t >> 5;  // 0..7

  float invp = 0.f;
  for (int g = gs; g < GSZ; g += 8) {
    float x = Eq[((size_t)g * NPT + n) * 64 + c];
    invp += x;
    float ss = x * x;
#pragma unroll
    for (int m = 16; m >= 1; m >>= 1) ss += __shfl_xor(ss, m, 64);
    float nrm = sqrtf(ss);
    nrm = nrm > 1e-4f ? nrm : 1e-4f;
    out[16384 + ((size_t)n * 32 + c) * GSZ + g] = x / nrm;
  }

  __shared__ float tmp[8][32];
  tmp[gs][c] = invp;
  __syncthreads();
  if (t < 32) {
    float s = 0.f;
#pragma unroll
    for (int i = 0; i < 8; ++i) s += tmp[i][t];
    s *= (1.f / 60.f);
    float ss = s * s;
#pragma unroll
    for (int m = 16; m >= 1; m >>= 1) ss += __shfl_xor(ss, m, 64);
    float nrm = sqrtf(ss);
    nrm = nrm > 1e-4f ? nrm : 1e-4f;
    out[(size_t)n * 32 + t] = s / nrm;
  }
}

extern "C" void kernel_launch(void* const* d_in, const int* in_sizes, int n_in,
                              void* d_out, int out_size, void* d_ws, size_t ws_size,
                              hipStream_t stream) {
  const float* feats = (const float*)d_in[0];
  const int* nei = (const int*)d_in[1];
  const float* W_in = (const float*)d_in[2];
  const float* b_in = (const float*)d_in[3];
  const float* W_r1 = (const float*)d_in[4];
  const float* b_r1 = (const float*)d_in[5];
  const float* W_r2 = (const float*)d_in[6];
  const float* b_r2 = (const float*)d_in[7];
  const float* W_out = (const float*)d_in[8];
  const float* b_out = (const float*)d_in[9];
  float* out = (float*)d_out;

  char* ws = (char*)d_ws;
  size_t off = 0;
  auto alloc = [&](size_t bytes) {
    void* p = ws + off;
    off += (bytes + 255) & ~(size_t)255;
    return p;
  };
  ushort* X0 = (ushort*)alloc((size_t)61 * NPT * 32 * 2);      // 2.0 MB (panel 60 = zeros)
  ushort* H1 = (ushort*)alloc((size_t)GSZ * NPT * 256 * 2);    // 15.7 MB (h1, then h2 in-place)
  ushort* R = (ushort*)alloc((size_t)GSZ * NPT * 512 * 2);     // 31.5 MB
  float* Eq = (float*)alloc((size_t)GSZ * NPT * 64 * 4);       // 7.9 MB
  ushort* Wb_in = (ushort*)alloc((size_t)256 * 448 * 2);
  ushort* Wb_r1 = (ushort*)alloc((size_t)512 * 3328 * 2);
  ushort* Wb_r2 = (ushort*)alloc((size_t)256 * 6656 * 2);
  ushort* Wb_out = (ushort*)alloc((size_t)64 * 3328 * 2);

  prep_feats_k<<<(61 * NPT * 32 + 255) / 256, 256, 0, stream>>>(feats, X0);
  prep_wb_k<<<(256 * 448 + 255) / 256, 256, 0, stream>>>(W_in, Wb_in, 256, 256, 32, 448);
  prep_wb_k<<<(512 * 3328 + 255) / 256, 256, 0, stream>>>(W_r1, Wb_r1, 512, 512, 256, 3328);
  prep_wb_k<<<(256 * 6656 + 255) / 256, 256, 0, stream>>>(W_r2, Wb_r2, 256, 256, 512, 6656);
  prep_wb_k<<<(64 * 3328 + 255) / 256, 256, 0, stream>>>(W_out, Wb_out, 32, 64, 256, 3328);

  dim3 blk(256);
  // L1: 32 -> 256 (KTOT 416 padded to 448)
  comb_gemm<32, 448, 256, 256, 128, 0, false><<<dim3(2 * 4 * GSZ), blk, 0, stream>>>(
      X0, Wb_in, b_in, nei, H1, nullptr, nullptr);
  // L2: 256 -> 512, relu
  comb_gemm<256, 3328, 512, 512, 128, 0, true><<<dim3(4 * 4 * GSZ), blk, 0, stream>>>(
      H1, Wb_r1, b_r1, nei, R, nullptr, nullptr);
  // L3: 512 -> 256, h2 = h1 + comb(r) in-place
  comb_gemm<512, 6656, 256, 256, 128, 1, false><<<dim3(2 * 4 * GSZ), blk, 0, stream>>>(
      R, Wb_r2, b_r2, nei, H1, nullptr, nullptr);
  // L4: 256 -> 32 (pad 64), + feats -> Eq fp32
  comb_gemm<256, 3328, 64, 32, 64, 2, false><<<dim3(1 * 4 * GSZ), blk, 0, stream>>>(
      H1, Wb_out, b_out, nei, nullptr, Eq, feats);
  finalize_k<<<NPT, 256, 0, stream>>>(Eq, out);
}

// Round 3
// 325.255 us; speedup vs baseline: 2.1255x; 1.0940x over previous
//
#include <hip/hip_runtime.h>
#include <stdint.h>

#define GSZ 60
#define KNB 13
#define NPT 512

typedef __attribute__((ext_vector_type(4))) float f32x4;
typedef __attribute__((ext_vector_type(8))) short s16x8;

__device__ __forceinline__ ushort f2bf(float f) {
  union { float f; unsigned u; } v; v.f = f;
  unsigned r = v.u + 0x7fffu + ((v.u >> 16) & 1u);
  return (ushort)(r >> 16);
}
__device__ __forceinline__ float bf2f(ushort h) {
  union { unsigned u; float f; } v; v.u = ((unsigned)h) << 16;
  return v.f;
}

// async global->LDS, 16B per lane; dst must be wave-uniform (HW adds lane*16)
__device__ __forceinline__ void gload_lds16(const void* gsrc, void* ldst) {
  __builtin_amdgcn_global_load_lds(
      (const __attribute__((address_space(1))) uint32_t*)gsrc,
      (__attribute__((address_space(3))) uint32_t*)ldst, 16, 0, 0);
}

// feats [N][32][G] fp32 -> X0 [61][N][32] bf16 (panel 60 = zeros, L1 K-padding)
__global__ __launch_bounds__(256) void prep_feats_k(const float* __restrict__ feats,
                                                    ushort* __restrict__ X0) {
  int idx = blockIdx.x * 256 + threadIdx.x;
  if (idx >= 61 * NPT * 32) return;
  int c = idx & 31;
  int t = idx >> 5;
  int n = t % NPT;
  int g = t / NPT;
  X0[idx] = (g < GSZ) ? f2bf(feats[(n * 32 + c) * GSZ + g]) : (ushort)0;
}

// W [O][C][13] fp32 -> Wb [OPAD][KPAD] bf16, Wb[o][k*C+c] = W[o][c][k], zero-padded
__global__ __launch_bounds__(256) void prep_wb_k(const float* __restrict__ W,
                                                 ushort* __restrict__ Wb,
                                                 int O, int OPAD, int C, int KPAD) {
  int idx = blockIdx.x * 256 + threadIdx.x;
  if (idx >= OPAD * KPAD) return;
  int o = idx / KPAD;
  int kk = idx - o * KPAD;
  int k = kk / C;
  int c = kk - k * C;
  Wb[idx] = (o < O && k < KNB) ? f2bf(W[(o * C + c) * KNB + k]) : (ushort)0;
}

// out[g][n][o] = sum_kk Xin[nei[g, kk/CIN]][n][kk%CIN] * Wb[o][kk]
// 2-phase pipelined (catalog T3-lite): double-buffered LDS, STAGE(next) issued
// before compute(cur), one vmcnt(0)+barrier per chunk. XOR-swizzled LDS
// (linear dest + inverse-swizzled global source + swizzled ds_read).
template <int CIN, int KTOT, int OPAD, int OREAL, int BN, int MODE, bool RELU>
__global__ __launch_bounds__(256) void comb_gemm(
    const ushort* __restrict__ Xin,   // [P][NPT][CIN] bf16 panels
    const ushort* __restrict__ Wb,    // [OPAD][KTOT] bf16
    const float* __restrict__ bias,
    const int* __restrict__ nei,      // [G*13]
    ushort* __restrict__ Xout,        // modes 0/1: [G][NPT][OPAD]
    float* __restrict__ Eq,           // mode 2: [G][NPT][64] fp32
    const float* __restrict__ feats)  // mode 2: [N][32][G] fp32
{
  constexpr int BM = 128;
  constexpr int BK = 64;
  constexpr int NCH = KTOT / BK;
  constexpr int TO = OPAD / BN;
  constexpr int TN = NPT / BM;  // 4
  constexpr int WN = BN / 2;    // per-wave n-width
  constexpr int N_REP = WN / 16;
  constexpr int M_REP = 4;  // 64/16
  constexpr int CSH = (CIN == 32) ? 5 : (CIN == 256) ? 8 : 9;
  static_assert(CIN == (1 << CSH), "CIN pow2");

  __shared__ ushort smA[2][BM * BK];
  __shared__ ushort smB[2][BN * BK];
  __shared__ int nei_sh[16];

  // XCD-chunked swizzle: consecutive idx (same g) land on the same XCD,
  // so the 13 gathered A-panels of a g stay resident in that XCD's L2.
  const int nwg = TO * TN * GSZ;
  const int cpx = nwg >> 3;
  const int bid = blockIdx.x;
  const int idx = (bid & 7) * cpx + (bid >> 3);
  const int g = idx / (TO * TN);
  const int rem = idx - g * (TO * TN);
  const int nt = rem / TO;
  const int ot = rem - nt * TO;
  const int n0 = nt * BM;
  const int o0 = ot * BN;

  const int t = threadIdx.x;
  if (t < 14) nei_sh[t] = (t < KNB) ? nei[g * KNB + t] : GSZ;  // 13 -> zero panel
  __syncthreads();

  const int w = t >> 6;
  const int l = t & 63;
  const int lrow = l & 15;
  const int lkg = l >> 4;
  const int wr = w >> 1;
  const int wc = w & 1;
  const int srow_w = w * 8;   // wave-uniform row base
  const int sr = l >> 3;      // lane row 0..7 within wave
  const int slot = l & 7;     // 16B slot 0..7

  // chunk-invariant per-lane staging offsets (elements)
  int laneA[BM / 32], laneB[BN / 32], swz[BM / 32];
#pragma unroll
  for (int j = 0; j < BM / 32; ++j) {
    const int r = j * 32 + srow_w + sr;
    swz[j] = (slot ^ (r & 7)) << 3;
    laneA[j] = ((n0 + r) << CSH) + swz[j];
  }
#pragma unroll
  for (int j = 0; j < BN / 32; ++j) {
    const int r = j * 32 + srow_w + sr;
    laneB[j] = (o0 + r) * KTOT + ((slot ^ (r & 7)) << 3);
  }

  auto stage = [&](int buf, int q) {
    const int c0 = q * BK;
    if constexpr (CIN >= 64) {
      // neighbor index wave-uniform per chunk (BK=64 never crosses a panel)
      const int pbase = nei_sh[c0 >> CSH] * (NPT << CSH) + (c0 & (CIN - 1));
#pragma unroll
      for (int j = 0; j < BM / 32; ++j)
        gload_lds16(Xin + pbase + laneA[j], &smA[buf][(j * 32 + srow_w) * BK]);
    } else {
#pragma unroll
      for (int j = 0; j < BM / 32; ++j) {
        const int r = j * 32 + srow_w + sr;
        const int kk = c0 + swz[j];
        const int nbr = kk >> CSH;
        const int cc = kk & (CIN - 1);
        gload_lds16(Xin + ((nei_sh[nbr] * NPT + n0 + r) << CSH) + cc,
                    &smA[buf][(j * 32 + srow_w) * BK]);
      }
    }
#pragma unroll
    for (int j = 0; j < BN / 32; ++j)
      gload_lds16(Wb + laneB[j] + c0, &smB[buf][(j * 32 + srow_w) * BK]);
  };

  f32x4 acc[M_REP][N_REP] = {};

  // prologue
  stage(0, 0);
  asm volatile("s_waitcnt vmcnt(0)" ::: "memory");
  __builtin_amdgcn_s_barrier();

  int cur = 0;
#pragma unroll 1
  for (int q = 0; q < NCH; ++q) {
    if (q + 1 < NCH) stage(cur ^ 1, q + 1);
#pragma unroll
    for (int ks = 0; ks < 2; ++ks) {
      const int cb = ks * 4 + lkg;
      s16x8 bf[N_REP];
#pragma unroll
      for (int n = 0; n < N_REP; ++n) {
        const int r = wc * WN + n * 16 + lrow;
        bf[n] = *(const s16x8*)&smB[cur][r * BK + ((cb ^ (r & 7)) << 3)];
      }
#pragma unroll
      for (int m = 0; m < M_REP; ++m) {
        const int r = wr * 64 + m * 16 + lrow;
        s16x8 af = *(const s16x8*)&smA[cur][r * BK + ((cb ^ (r & 7)) << 3)];
#pragma unroll
        for (int n = 0; n < N_REP; ++n)
          acc[m][n] = __builtin_amdgcn_mfma_f32_16x16x32_bf16(af, bf[n], acc[m][n], 0, 0, 0);
      }
    }
    asm volatile("s_waitcnt vmcnt(0)" ::: "memory");
    __builtin_amdgcn_s_barrier();
    cur ^= 1;
  }

#pragma unroll
  for (int m = 0; m < M_REP; ++m) {
#pragma unroll
    for (int n = 0; n < N_REP; ++n) {
      const int oc = o0 + wc * WN + n * 16 + lrow;
      float bv;
      if (MODE == 2)
        bv = (oc < OREAL) ? bias[oc] : 0.f;
      else
        bv = bias[oc];
#pragma unroll
      for (int r = 0; r < 4; ++r) {
        const int row = n0 + wr * 64 + m * 16 + lkg * 4 + r;
        float v = acc[m][n][r] + bv;
        if (MODE == 0) {
          if (RELU) v = v > 0.f ? v : 0.f;
          Xout[((size_t)g * NPT + row) * OPAD + oc] = f2bf(v);
        } else if (MODE == 1) {
          const size_t ix = ((size_t)g * NPT + row) * OPAD + oc;
          Xout[ix] = f2bf(bf2f(Xout[ix]) + v);
        } else {
          const float add = (oc < OREAL) ? feats[((size_t)row * 32 + oc) * GSZ + g] : 0.f;
          Eq[((size_t)g * NPT + row) * 64 + oc] = v + add;
        }
      }
    }
  }
}

// Eq [G][N][64] fp32 -> out: inv [N][32] normalized, eqv [N][32][G] normalized
__global__ __launch_bounds__(256) void finalize_k(const float* __restrict__ Eq,
                                                  float* __restrict__ out) {
  const int n = blockIdx.x;
  const int t = threadIdx.x;
  const int c = t & 31;
  const int gs = t >> 5;  // 0..7

  float invp = 0.f;
  for (int g = gs; g < GSZ; g += 8) {
    float x = Eq[((size_t)g * NPT + n) * 64 + c];
    invp += x;
    float ss = x * x;
#pragma unroll
    for (int m = 16; m >= 1; m >>= 1) ss += __shfl_xor(ss, m, 64);
    float nrm = sqrtf(ss);
    nrm = nrm > 1e-4f ? nrm : 1e-4f;
    out[16384 + ((size_t)n * 32 + c) * GSZ + g] = x / nrm;
  }

  __shared__ float tmp[8][32];
  tmp[gs][c] = invp;
  __syncthreads();
  if (t < 32) {
    float s = 0.f;
#pragma unroll
    for (int i = 0; i < 8; ++i) s += tmp[i][t];
    s *= (1.f / 60.f);
    float ss = s * s;
#pragma unroll
    for (int m = 16; m >= 1; m >>= 1) ss += __shfl_xor(ss, m, 64);
    float nrm = sqrtf(ss);
    nrm = nrm > 1e-4f ? nrm : 1e-4f;
    out[(size_t)n * 32 + t] = s / nrm;
  }
}

extern "C" void kernel_launch(void* const* d_in, const int* in_sizes, int n_in,
                              void* d_out, int out_size, void* d_ws, size_t ws_size,
                              hipStream_t stream) {
  const float* feats = (const float*)d_in[0];
  const int* nei = (const int*)d_in[1];
  const float* W_in = (const float*)d_in[2];
  const float* b_in = (const float*)d_in[3];
  const float* W_r1 = (const float*)d_in[4];
  const float* b_r1 = (const float*)d_in[5];
  const float* W_r2 = (const float*)d_in[6];
  const float* b_r2 = (const float*)d_in[7];
  const float* W_out = (const float*)d_in[8];
  const float* b_out = (const float*)d_in[9];
  float* out = (float*)d_out;

  char* ws = (char*)d_ws;
  size_t off = 0;
  auto alloc = [&](size_t bytes) {
    void* p = ws + off;
    off += (bytes + 255) & ~(size_t)255;
    return p;
  };
  ushort* X0 = (ushort*)alloc((size_t)61 * NPT * 32 * 2);      // 2.0 MB (panel 60 = zeros)
  ushort* H1 = (ushort*)alloc((size_t)GSZ * NPT * 256 * 2);    // 15.7 MB (h1, then h2 in-place)
  ushort* R = (ushort*)alloc((size_t)GSZ * NPT * 512 * 2);     // 31.5 MB
  float* Eq = (float*)alloc((size_t)GSZ * NPT * 64 * 4);       // 7.9 MB
  ushort* Wb_in = (ushort*)alloc((size_t)256 * 448 * 2);
  ushort* Wb_r1 = (ushort*)alloc((size_t)512 * 3328 * 2);
  ushort* Wb_r2 = (ushort*)alloc((size_t)256 * 6656 * 2);
  ushort* Wb_out = (ushort*)alloc((size_t)64 * 3328 * 2);

  prep_feats_k<<<(61 * NPT * 32 + 255) / 256, 256, 0, stream>>>(feats, X0);
  prep_wb_k<<<(256 * 448 + 255) / 256, 256, 0, stream>>>(W_in, Wb_in, 256, 256, 32, 448);
  prep_wb_k<<<(512 * 3328 + 255) / 256, 256, 0, stream>>>(W_r1, Wb_r1, 512, 512, 256, 3328);
  prep_wb_k<<<(256 * 6656 + 255) / 256, 256, 0, stream>>>(W_r2, Wb_r2, 256, 256, 512, 6656);
  prep_wb_k<<<(64 * 3328 + 255) / 256, 256, 0, stream>>>(W_out, Wb_out, 32, 64, 256, 3328);

  dim3 blk(256);
  // L1: 32 -> 256 (KTOT 416 padded to 448)
  comb_gemm<32, 448, 256, 256, 128, 0, false><<<dim3(2 * 4 * GSZ), blk, 0, stream>>>(
      X0, Wb_in, b_in, nei, H1, nullptr, nullptr);
  // L2: 256 -> 512, relu
  comb_gemm<256, 3328, 512, 512, 128, 0, true><<<dim3(4 * 4 * GSZ), blk, 0, stream>>>(
      H1, Wb_r1, b_r1, nei, R, nullptr, nullptr);
  // L3: 512 -> 256, h2 = h1 + comb(r) in-place
  comb_gemm<512, 6656, 256, 256, 128, 1, false><<<dim3(2 * 4 * GSZ), blk, 0, stream>>>(
      R, Wb_r2, b_r2, nei, H1, nullptr, nullptr);
  // L4: 256 -> 32 (pad 64), + feats -> Eq fp32
  comb_gemm<256, 3328, 64, 32, 64, 2, false><<<dim3(1 * 4 * GSZ), blk, 0, stream>>>(
      H1, Wb_out, b_out, nei, nullptr, Eq, feats);
  finalize_k<<<NPT, 256, 0, stream>>>(Eq, out);
}